// Round 1
// baseline (654.133 us; speedup 1.0000x reference)
//
#include <hip/hip_runtime.h>

// MeanAggregator: out[b,:] = mean over {neighbours[b,0..9], nodes[b]} of features[idx,:]
// B=100000, K=10, N=1000000, D=128. Pure memory-bound random gather.
//
// Layout v2: TWO nodes per 64-lane wave. Lanes 0-31 handle node A, lanes 32-63
// node B; each lane loads float4 (16B), so one global_load_dwordx4 moves 1 KB =
// two full 512B feature rows, both halves coalesced. Persistent waves (2048
// blocks) grid-stride over node pairs; the next pair's neighbour indices are
// issued while the current gathers are in flight (they sit behind the gathers
// in vmcnt order, so accumulate only waits for the gathers). Output uses
// nontemporal stores to keep L2/L3 for the feature table.

#define KNEIGH 10
#define DDIM 128

typedef float v4f __attribute__((ext_vector_type(4)));

__global__ __launch_bounds__(256) void MeanAggregator_36386962932386_kernel(
    const int* __restrict__ nodes,
    const int* __restrict__ neighbours,
    const float* __restrict__ features,
    float* __restrict__ out,
    int B)
{
    const int wave = blockIdx.x * 4 + (threadIdx.x >> 6);
    const int lane = threadIdx.x & 63;
    const int half = lane >> 5;              // 0 -> node A, 1 -> node B
    const int hl   = lane & 31;              // lane within half-wave
    const unsigned hb = (unsigned)hl * 16u;  // byte offset within feature row

    const int npairs = (B + 1) >> 1;
    const int nwaves = gridDim.x * 4;

    int pair = wave;
    if (pair >= npairs) return;

    int idx[KNEIGH + 1];
    int node;

    // ---- load indices for the first pair (int2-vectorized: row = 10 ints, 8B-aligned) ----
    {
        node = pair * 2 + half;
        const int n = node < B ? node : 0;
        const int2* p2 = (const int2*)((const char*)neighbours + (unsigned)n * (KNEIGH * 4));
#pragma unroll
        for (int j = 0; j < KNEIGH / 2; ++j) {
            const int2 t = p2[j];
            idx[2 * j]     = t.x;
            idx[2 * j + 1] = t.y;
        }
        idx[KNEIGH] = nodes[n];
    }

    while (true) {
        // ---- issue all 11 gathers: each instruction = 1 KB (two random rows) ----
        v4f v[KNEIGH + 1];
#pragma unroll
        for (int j = 0; j < KNEIGH + 1; ++j) {
            const unsigned off = (unsigned)idx[j] * (DDIM * 4) + hb;
            v[j] = *(const v4f*)((const char*)features + off);
        }

        // ---- prefetch next pair's indices while gathers are in flight ----
        const int next = pair + nwaves;
        const bool have_next = next < npairs;
        int nidx[KNEIGH + 1];
        int nnode = 0;
        if (have_next) {
            nnode = next * 2 + half;
            const int n = nnode < B ? nnode : 0;
            const int2* p2 = (const int2*)((const char*)neighbours + (unsigned)n * (KNEIGH * 4));
#pragma unroll
            for (int j = 0; j < KNEIGH / 2; ++j) {
                const int2 t = p2[j];
                nidx[2 * j]     = t.x;
                nidx[2 * j + 1] = t.y;
            }
            nidx[KNEIGH] = nodes[n];
        }

        // ---- accumulate (waits only on the gathers; index loads stay in flight) ----
        v4f acc = v[0];
#pragma unroll
        for (int j = 1; j < KNEIGH + 1; ++j) acc += v[j];
        acc *= (1.0f / (KNEIGH + 1));

        if (node < B) {
            const unsigned ooff = (unsigned)node * (DDIM * 4) + hb;
            __builtin_nontemporal_store(acc, (v4f*)((char*)out + ooff));
        }

        if (!have_next) break;
        pair = next;
        node = nnode;
#pragma unroll
        for (int j = 0; j < KNEIGH + 1; ++j) idx[j] = nidx[j];
    }
}

extern "C" void kernel_launch(void* const* d_in, const int* in_sizes, int n_in,
                              void* d_out, int out_size, void* d_ws, size_t ws_size,
                              hipStream_t stream)
{
    const int* nodes      = (const int*)d_in[0];
    const int* neighbours = (const int*)d_in[1];
    const float* features = (const float*)d_in[2];
    float* out            = (float*)d_out;

    const int B = in_sizes[0];            // 100000
    const int npairs = (B + 1) / 2;       // two nodes per wave
    int blocks = (npairs + 3) / 4;        // 4 waves per block
    if (blocks > 2048) blocks = 2048;     // persistent waves, grid-stride

    MeanAggregator_36386962932386_kernel<<<blocks, 256, 0, stream>>>(
        nodes, neighbours, features, out, B);
}